// Round 12
// baseline (103.443 us; speedup 1.0000x reference)
//
#include <hip/hip_runtime.h>

#define K3 27
#define CIN 8
#define COUT 64
#define CC_EPS 1e-12f
#define CHUNK 32
#define RECW 12   // weight record: wab[9] (win-premultiplied a*b) + wc[3]

typedef float v2f __attribute__((ext_vector_type(2)));

static __device__ __forceinline__ v2f vfma2(v2f a, v2f b, v2f c) {
#if __has_builtin(__builtin_elementwise_fma)
    return __builtin_elementwise_fma(a, b, c);   // -> v_pk_fma_f32
#else
    return a * b + c;
#endif
}

// Block = 256 threads = 4 waves = ONE output point.
// Phase 1: cooperative ballot-compaction of inside-ball j's into shared idx[].
// Phase 2 per wave, chunks of 32 slots (stride 128):
//   prefetch: idx + features (v2f, 2 channels/lane) for both rounds, issued
//             BEFORE stage A so global latency hides under geometry.
//   stage A: lane(<32) computes ONE slot's geometry -> 12-float LDS record.
//   stage B: 16 groups x 4 lanes; round t: group g4 consumes record t*16+g4
//            (b128 broadcast reads), 27 packed FMA covering 2 channels/lane.
//   Same-wave ds_write -> ds_read needs no barrier (per-wave DS FIFO).
// Epilogue: shfl-reduce over groups, cross-wave sum, 4-way k-split GEMM, relu.
__global__ __launch_bounds__(256, 5)
void cconv_fused_kernel(const float* __restrict__ features,
                        const float* __restrict__ pos_input,
                        const float* __restrict__ pos_output,
                        const float* __restrict__ extents,
                        const float* __restrict__ kern,
                        const float* __restrict__ bias,
                        float* __restrict__ out,
                        int Ni, int No)
{
    const int tid  = threadIdx.x;
    const int w    = tid >> 6;        // wave 0..3
    const int lane = tid & 63;
    const int g4   = lane >> 2;       // 16 groups of 4 lanes
    const int c2   = lane & 3;        // channel pair: channels 2*c2, 2*c2+1
    const int i    = blockIdx.x;      // output point

    // carved LDS: idx[2048] ushort (aliased by part[4][COUT] in epilogue),
    // wrec[4][CHUNK][RECW] f32, Bsh[4][K3][CIN] f32
    __shared__ __align__(16) char smem[4096 + 4*CHUNK*RECW*4 + 4*K3*CIN*4];
    unsigned short* idx  = (unsigned short*)smem;
    float*          part = (float*)smem;                            // aliases idx
    float*          wrec = (float*)(smem + 4096);
    float*          Bsh  = (float*)(smem + 4096 + 4*CHUNK*RECW*4);
    __shared__ int cnt_sh;

    if (tid == 0) cnt_sh = 0;
    __syncthreads();

    const float s  = 2.0f / extents[0];
    const float ox = pos_output[i*3+0];
    const float oy = pos_output[i*3+1];
    const float oz = pos_output[i*3+2];

    // ---------------- Phase 1: cooperative ballot compaction ----------------
    for (int j0 = w*64; j0 < Ni; j0 += 256) {
        const int j = j0 + lane;
        bool inside = false;
        if (j < Ni) {
            const float rx = (pos_input[j*3+0]-ox)*s;
            const float ry = (pos_input[j*3+1]-oy)*s;
            const float rz = (pos_input[j*3+2]-oz)*s;
            inside = (rx*rx + ry*ry + rz*rz) < 1.0f;
        }
        const unsigned long long m = __ballot(inside);
        const int nin = (int)__popcll(m);
        int base = 0;
        if (lane == 0 && nin) base = atomicAdd(&cnt_sh, nin);
        base = __shfl(base, 0, 64);
        if (inside) {
            const int pre = __popcll(m & ((1ull<<lane)-1ull));
            idx[base+pre] = (unsigned short)j;
        }
    }
    __syncthreads();
    const int total = cnt_sh;

    // ---------------- Phase 2 ----------------
    v2f acc[K3];
#pragma unroll
    for (int k = 0; k < K3; ++k) acc[k] = (v2f){0.0f, 0.0f};

    for (int cb = w*CHUNK; cb < total; cb += 4*CHUNK) {
        // ---- prefetch stage-B inputs (before stage A: hides global latency)
        const int sl0 = cb + g4;
        const int sl1 = cb + 16 + g4;
        const int jj0 = idx[(sl0 < total) ? sl0 : 0];
        const int jj1 = idx[(sl1 < total) ? sl1 : 0];
        const v2f fv0 = *(const v2f*)(features + jj0*CIN + 2*c2);
        const v2f fv1 = *(const v2f*)(features + jj1*CIN + 2*c2);

        // ---- stage A: one lane per slot, geometry -> 12-float record
        if (lane < CHUNK) {
            const int  slot = cb + lane;
            const bool va   = slot < total;
            const int  j    = idx[va ? slot : 0];
            float ab0=0,ab1=0,ab2=0,ab3=0,ab4=0,ab5=0,ab6=0,ab7=0,ab8=0;
            float wc0=0,wc1=0,wc2=0;
            if (va) {
                const float rx = (pos_input[j*3+0]-ox)*s;   // comp0 -> stride 9
                const float ry = (pos_input[j*3+1]-oy)*s;   // comp1 -> stride 3
                const float rz = (pos_input[j*3+2]-oz)*s;   // comp2 -> stride 1
                const float r2  = rx*rx + ry*ry + rz*rz;    // < 1 guaranteed
                const float u   = 1.0f - r2;
                const float win = u*u*u;                    // poly6 window
                const float r    = __builtin_amdgcn_sqrtf(fmaxf(r2, CC_EPS));
                const float linf = fmaxf(fmaxf(fabsf(rx), fabsf(ry)), fabsf(rz));
                const float scale = (linf > CC_EPS) ? r*__builtin_amdgcn_rcpf(linf) : 1.0f;
                const float ta = fminf(fmaxf(rx*scale, -1.f), 1.f) + 1.0f;
                const float tb = fminf(fmaxf(ry*scale, -1.f), 1.f) + 1.0f;
                const float tc = fminf(fmaxf(rz*scale, -1.f), 1.f) + 1.0f;
                // 1-D trilinear over 3 bins: t<1:{1-t,t,0}, t>=1:{0,2-t,t-1}
                const float wa0 = fmaxf(1.0f-ta, 0.0f), wa2 = fmaxf(ta-1.0f, 0.0f);
                const float wb0 = fmaxf(1.0f-tb, 0.0f), wb2 = fmaxf(tb-1.0f, 0.0f);
                wc0 = fmaxf(1.0f-tc, 0.0f); wc2 = fmaxf(tc-1.0f, 0.0f);
                const float wa1 = 1.0f - wa0 - wa2;
                const float wb1 = 1.0f - wb0 - wb2;
                wc1 = 1.0f - wc0 - wc2;
                const float a0 = wa0*win, a1 = wa1*win, a2 = wa2*win;
                ab0 = a0*wb0; ab1 = a0*wb1; ab2 = a0*wb2;
                ab3 = a1*wb0; ab4 = a1*wb1; ab5 = a1*wb2;
                ab6 = a2*wb0; ab7 = a2*wb1; ab8 = a2*wb2;
            }
            float* rec = wrec + (w*CHUNK + lane)*RECW;
            ((float4*)rec)[0] = make_float4(ab0, ab1, ab2, ab3);
            ((float4*)rec)[1] = make_float4(ab4, ab5, ab6, ab7);
            ((float4*)rec)[2] = make_float4(ab8, wc0, wc1, wc2);
        }
        // same-wave ds_write -> ds_read: DS ops execute in order per wave;
        // no barrier / waitcnt needed.

        // ---- stage B round 0: record l = g4
        {
            const float* rec = wrec + (w*CHUNK + g4)*RECW;
            const float4 r0 = ((const float4*)rec)[0];
            const float4 r1 = ((const float4*)rec)[1];
            const float4 r2 = ((const float4*)rec)[2];
            const v2f p0 = r2.y * fv0, p1 = r2.z * fv0, p2 = r2.w * fv0;
            const float wabv[9] = { r0.x, r0.y, r0.z, r0.w,
                                    r1.x, r1.y, r1.z, r1.w, r2.x };
#pragma unroll
            for (int ab = 0; ab < 9; ++ab) {
                const v2f wsp = { wabv[ab], wabv[ab] };
                acc[ab*3+0] = vfma2(wsp, p0, acc[ab*3+0]);
                acc[ab*3+1] = vfma2(wsp, p1, acc[ab*3+1]);
                acc[ab*3+2] = vfma2(wsp, p2, acc[ab*3+2]);
            }
        }
        // ---- stage B round 1: record l = 16 + g4
        {
            const float* rec = wrec + (w*CHUNK + 16 + g4)*RECW;
            const float4 r0 = ((const float4*)rec)[0];
            const float4 r1 = ((const float4*)rec)[1];
            const float4 r2 = ((const float4*)rec)[2];
            const v2f p0 = r2.y * fv1, p1 = r2.z * fv1, p2 = r2.w * fv1;
            const float wabv[9] = { r0.x, r0.y, r0.z, r0.w,
                                    r1.x, r1.y, r1.z, r1.w, r2.x };
#pragma unroll
            for (int ab = 0; ab < 9; ++ab) {
                const v2f wsp = { wabv[ab], wabv[ab] };
                acc[ab*3+0] = vfma2(wsp, p0, acc[ab*3+0]);
                acc[ab*3+1] = vfma2(wsp, p1, acc[ab*3+1]);
                acc[ab*3+2] = vfma2(wsp, p2, acc[ab*3+2]);
            }
        }
    }

    // within-wave reduce over groups (lane bits 2..5); g4==0 lanes hold result
#pragma unroll
    for (int k = 0; k < K3; ++k) {
        float vx = acc[k].x, vy = acc[k].y;
        vx += __shfl_xor(vx, 4, 64);  vy += __shfl_xor(vy, 4, 64);
        vx += __shfl_xor(vx, 8, 64);  vy += __shfl_xor(vy, 8, 64);
        vx += __shfl_xor(vx, 16, 64); vy += __shfl_xor(vy, 16, 64);
        vx += __shfl_xor(vx, 32, 64); vy += __shfl_xor(vy, 32, 64);
        if (g4 == 0) {
            Bsh[(w*K3 + k)*CIN + 2*c2]     = vx;
            Bsh[(w*K3 + k)*CIN + 2*c2 + 1] = vy;
        }
    }
    __syncthreads();

    // cross-wave sum into Bsh[0]
    if (tid < K3*CIN) {
        const int k  = tid >> 3;
        const int cc = tid & 7;
        Bsh[k*CIN + cc] = Bsh[k*CIN + cc]
                        + Bsh[(K3   + k)*CIN + cc]
                        + Bsh[(2*K3 + k)*CIN + cc]
                        + Bsh[(3*K3 + k)*CIN + cc];
    }
    __syncthreads();

    // ---------------- Epilogue: out = relu(B . kernel + bias), 4-way k-split
    {
        const int kb = w*7;
        const int ke = (kb + 7 < K3) ? kb + 7 : K3;
        float o = 0.0f;
        for (int k = kb; k < ke; ++k) {
#pragma unroll
            for (int cc = 0; cc < CIN; ++cc) {
                o = fmaf(Bsh[k*CIN + cc], kern[(k*CIN + cc)*COUT + lane], o);
            }
        }
        part[w*COUT + lane] = o;    // part aliases idx (idx dead after phase 2)
    }
    __syncthreads();

    if (tid < COUT) {
        const float o = bias[tid] + part[tid] + part[COUT + tid]
                      + part[2*COUT + tid] + part[3*COUT + tid];
        out[i*COUT + tid] = fmaxf(o, 0.0f);
    }
}

extern "C" void kernel_launch(void* const* d_in, const int* in_sizes, int n_in,
                              void* d_out, int out_size, void* d_ws, size_t ws_size,
                              hipStream_t stream) {
    const float* features   = (const float*)d_in[0];
    const float* pos_input  = (const float*)d_in[1];
    const float* pos_output = (const float*)d_in[2];
    const float* extents    = (const float*)d_in[3];
    const float* kern       = (const float*)d_in[4];
    const float* bias       = (const float*)d_in[5];
    float* out = (float*)d_out;

    const int Ni = in_sizes[0] / CIN;   // 2048 (idx cap assumes Ni <= 2048)
    const int No = in_sizes[2] / 3;

    dim3 block(256);
    dim3 grid(No);
    cconv_fused_kernel<<<grid, block, 0, stream>>>(features, pos_input, pos_output,
                                                   extents, kern, bias, out, Ni, No);
}